// Round 5
// baseline (812.306 us; speedup 1.0000x reference)
//
#include <hip/hip_runtime.h>
#include <hip/hip_bf16.h>
#include <cmath>

#define N_NODES 50000
#define IN_F 64
#define L 128
#define STEPS 3
#define T_TYPES 4
#define E_EDGES 800000

typedef __attribute__((ext_vector_type(8))) __bf16 bf16x8_t;
typedef __attribute__((ext_vector_type(4))) float f32x4;

__device__ inline float bf2f(ushort u) {
  union { uint i; float f; } v; v.i = ((uint)u) << 16; return v.f;
}
__device__ inline ushort f2bf(float f) {
  union { float f; uint u; } v; v.f = f;
  uint u = v.u;
  u += 0x7fffu + ((u >> 16) & 1u);  // RNE
  return (ushort)(u >> 16);
}

// ---------------- fp32 tiled matmul for x0 (K=64), writes bf16 ----------------
#define BN 64
#define BO 64
#define BK 16
__global__ __launch_bounds__(256) void matmul_x0(
    const float* __restrict__ A, const float* __restrict__ W,
    const float* __restrict__ bias, ushort* __restrict__ Cb,
    int N, int K, int OUT)
{
  __shared__ float As[BN][BK + 1];
  __shared__ float Ws[BO][BK + 1];
  const int tid = threadIdx.x;
  const int n_base = blockIdx.x * BN;
  const int o_base = blockIdx.y * BO;
  const int tx = tid & 15, ty = tid >> 4;
  const int n0 = ty * 4, o0 = tx * 4;
  const int lr = tid >> 2, lc = (tid & 3) * 4;
  float acc[4][4] = {{0.f, 0.f, 0.f, 0.f}};
  for (int kc = 0; kc < K; kc += BK) {
    int gn = n_base + lr;
    float4 av = make_float4(0.f, 0.f, 0.f, 0.f);
    if (gn < N) av = *(const float4*)(A + (size_t)gn * K + kc + lc);
    As[lr][lc + 0] = av.x; As[lr][lc + 1] = av.y;
    As[lr][lc + 2] = av.z; As[lr][lc + 3] = av.w;
    float4 wv = *(const float4*)(W + (size_t)(o_base + lr) * K + kc + lc);
    Ws[lr][lc + 0] = wv.x; Ws[lr][lc + 1] = wv.y;
    Ws[lr][lc + 2] = wv.z; Ws[lr][lc + 3] = wv.w;
    __syncthreads();
#pragma unroll
    for (int kk = 0; kk < BK; ++kk) {
      float a[4], w[4];
#pragma unroll
      for (int i = 0; i < 4; ++i) a[i] = As[n0 + i][kk];
#pragma unroll
      for (int j = 0; j < 4; ++j) w[j] = Ws[o0 + j][kk];
#pragma unroll
      for (int i = 0; i < 4; ++i)
#pragma unroll
        for (int j = 0; j < 4; ++j) acc[i][j] += a[i] * w[j];
    }
    __syncthreads();
  }
#pragma unroll
  for (int i = 0; i < 4; ++i) {
    int gn = n_base + n0 + i;
    if (gn >= N) continue;
    int o = o_base + o0;
    float v0 = fmaxf(acc[i][0] + bias[o + 0], 0.f);
    float v1 = fmaxf(acc[i][1] + bias[o + 1], 0.f);
    float v2 = fmaxf(acc[i][2] + bias[o + 2], 0.f);
    float v3 = fmaxf(acc[i][3] + bias[o + 3], 0.f);
    uint2 pk;
    pk.x = (uint)f2bf(v0) | ((uint)f2bf(v1) << 16);
    pk.y = (uint)f2bf(v2) | ((uint)f2bf(v3) << 16);
    *(uint2*)(Cb + (size_t)gn * OUT + o) = pk;
  }
}

// ---------------- MFMA GEMM: A[N,K] @ W[OUT,K]^T, 32 rows/wave ----------------
// KIND 0: bf16 out + bias (gh, K=128). KIND 2: bf16 out, no bias (S-gemm, K=512).
// KIND 3: GRU gate-triple epilogue -> m bf16 (K=128). KIND 4: heads mu/lv f32 (K=128).
template<int OUT, int K, int KIND>
__global__ __launch_bounds__(256) void gemm_mfma(
    const ushort* __restrict__ A, const ushort* __restrict__ W,
    const float* __restrict__ bias, float* __restrict__ Cf,
    ushort* __restrict__ Cb, const ushort* __restrict__ ghb,
    const ushort* __restrict__ x0b, const float* __restrict__ bias2,
    float* __restrict__ Cf2, int N)
{
  constexpr int NOT = OUT / 16;
  constexpr int NKT = K / 32;
  const int lane = threadIdx.x & 63;
  const int wave = threadIdx.x >> 6;
  const int r = lane & 15;
  const int kg = lane >> 4;
  const int row0 = (blockIdx.x * 8 + wave * 2) * 16;  // 2 row-tiles per wave
  if (row0 >= N) return;

  int arow0 = row0 + r;          if (arow0 >= N) arow0 = N - 1;
  int arow1 = row0 + 16 + r;     if (arow1 >= N) arow1 = N - 1;
  const ushort* ap0 = A + (size_t)arow0 * K + kg * 8;
  const ushort* ap1 = A + (size_t)arow1 * K + kg * 8;
  const ushort* wp = W + (size_t)r * K + kg * 8;

  if constexpr (KIND == 2) {
    // K-outer structure: W and A each read exactly once per wave.
    f32x4 acc[2][NOT];
#pragma unroll
    for (int rt = 0; rt < 2; ++rt)
#pragma unroll
      for (int ot = 0; ot < NOT; ++ot) acc[rt][ot] = {0.f, 0.f, 0.f, 0.f};
#pragma unroll
    for (int kt = 0; kt < NKT; ++kt) {
      bf16x8_t a0 = *(const bf16x8_t*)(ap0 + kt * 32);
      bf16x8_t a1 = *(const bf16x8_t*)(ap1 + kt * 32);
#pragma unroll
      for (int ot = 0; ot < NOT; ++ot) {
        bf16x8_t w = *(const bf16x8_t*)(wp + (size_t)ot * 16 * K + kt * 32);
        acc[0][ot] = __builtin_amdgcn_mfma_f32_16x16x32_bf16(a0, w, acc[0][ot], 0, 0, 0);
        acc[1][ot] = __builtin_amdgcn_mfma_f32_16x16x32_bf16(a1, w, acc[1][ot], 0, 0, 0);
      }
    }
#pragma unroll
    for (int rt = 0; rt < 2; ++rt)
#pragma unroll
      for (int ot = 0; ot < NOT; ++ot) {
        int o = ot * 16 + r;
#pragma unroll
        for (int reg = 0; reg < 4; ++reg) {
          int n = row0 + rt * 16 + kg * 4 + reg;
          if (n >= N) continue;
          Cb[(size_t)n * OUT + o] = f2bf(acc[rt][ot][reg]);
        }
      }
  } else if constexpr (KIND != 3) {
    bf16x8_t af[2][4];
#pragma unroll
    for (int kt = 0; kt < 4; ++kt) {
      af[0][kt] = *(const bf16x8_t*)(ap0 + kt * 32);
      af[1][kt] = *(const bf16x8_t*)(ap1 + kt * 32);
    }
#pragma unroll
    for (int otp = 0; otp < NOT / 2; ++otp) {
      bf16x8_t w0[4], w1[4];
#pragma unroll
      for (int kt = 0; kt < 4; ++kt) {
        w0[kt] = *(const bf16x8_t*)(wp + (size_t)(2 * otp) * 16 * K + kt * 32);
        w1[kt] = *(const bf16x8_t*)(wp + (size_t)(2 * otp + 1) * 16 * K + kt * 32);
      }
      f32x4 acc[2][2] = {{{0.f,0.f,0.f,0.f},{0.f,0.f,0.f,0.f}},
                         {{0.f,0.f,0.f,0.f},{0.f,0.f,0.f,0.f}}};
#pragma unroll
      for (int kt = 0; kt < 4; ++kt) {
#pragma unroll
        for (int rt = 0; rt < 2; ++rt) {
          acc[rt][0] = __builtin_amdgcn_mfma_f32_16x16x32_bf16(af[rt][kt], w0[kt], acc[rt][0], 0, 0, 0);
          acc[rt][1] = __builtin_amdgcn_mfma_f32_16x16x32_bf16(af[rt][kt], w1[kt], acc[rt][1], 0, 0, 0);
        }
      }
#pragma unroll
      for (int rt = 0; rt < 2; ++rt) {
#pragma unroll
        for (int oi = 0; oi < 2; ++oi) {
          int o = (2 * otp + oi) * 16 + r;
#pragma unroll
          for (int reg = 0; reg < 4; ++reg) {
            int n = row0 + rt * 16 + kg * 4 + reg;
            if (n >= N) continue;
            float v = acc[rt][oi][reg];
            if constexpr (KIND == 0) {
              Cb[(size_t)n * OUT + o] = f2bf(v + bias[o]);
            } else if constexpr (KIND == 4) {
              if (o < 128) Cf[(size_t)n * 128 + o] = v + bias[o];
              else Cf2[(size_t)n * 128 + (o - 128)] = v + bias2[o - 128];
            }
          }
        }
      }
    }
  } else {
    bf16x8_t af[2][4];
#pragma unroll
    for (int kt = 0; kt < 4; ++kt) {
      af[0][kt] = *(const bf16x8_t*)(ap0 + kt * 32);
      af[1][kt] = *(const bf16x8_t*)(ap1 + kt * 32);
    }
    // GRU: gate j cols live at out-tiles {jg, 8+jg, 16+jg}
#pragma unroll
    for (int jg = 0; jg < 8; ++jg) {
      bf16x8_t wr_[4], wz_[4], wn_[4];
#pragma unroll
      for (int kt = 0; kt < 4; ++kt) {
        wr_[kt] = *(const bf16x8_t*)(wp + (size_t)(jg) * 16 * K + kt * 32);
        wz_[kt] = *(const bf16x8_t*)(wp + (size_t)(8 + jg) * 16 * K + kt * 32);
        wn_[kt] = *(const bf16x8_t*)(wp + (size_t)(16 + jg) * 16 * K + kt * 32);
      }
      f32x4 ar[2] = {{0.f,0.f,0.f,0.f},{0.f,0.f,0.f,0.f}};
      f32x4 az[2] = {{0.f,0.f,0.f,0.f},{0.f,0.f,0.f,0.f}};
      f32x4 an[2] = {{0.f,0.f,0.f,0.f},{0.f,0.f,0.f,0.f}};
#pragma unroll
      for (int kt = 0; kt < 4; ++kt) {
#pragma unroll
        for (int rt = 0; rt < 2; ++rt) {
          ar[rt] = __builtin_amdgcn_mfma_f32_16x16x32_bf16(af[rt][kt], wr_[kt], ar[rt], 0, 0, 0);
          az[rt] = __builtin_amdgcn_mfma_f32_16x16x32_bf16(af[rt][kt], wz_[kt], az[rt], 0, 0, 0);
          an[rt] = __builtin_amdgcn_mfma_f32_16x16x32_bf16(af[rt][kt], wn_[kt], an[rt], 0, 0, 0);
        }
      }
      int j = jg * 16 + r;
      float br = bias[j], bz = bias[128 + j], bn = bias[256 + j];
#pragma unroll
      for (int rt = 0; rt < 2; ++rt) {
#pragma unroll
        for (int reg = 0; reg < 4; ++reg) {
          int n = row0 + rt * 16 + kg * 4 + reg;
          if (n >= N) continue;
          const ushort* ghp = ghb + (size_t)n * 384;
          float gir = ar[rt][reg] + br + bf2f(ghp[j]);
          float giz = az[rt][reg] + bz + bf2f(ghp[128 + j]);
          float ghn = bf2f(ghp[256 + j]);
          float rr = 1.f / (1.f + expf(-gir));
          float zz = 1.f / (1.f + expf(-giz));
          float nn = tanhf(an[rt][reg] + bn + rr * ghn);
          float x0v = bf2f(x0b[(size_t)n * 128 + j]);
          float h = (1.f - zz) * nn + zz * x0v;
          Cb[(size_t)n * 128 + j] = f2bf(fmaxf(h, 0.f));
        }
      }
    }
  }
}

// ---------------- weight conversion f32 -> bf16 (packed segments) ----------------
// Wg[s][c][t*128+j] = 2 * gnn_w[s][t][c][j]  (edge duplication factor folded in)
#define WOFF_WHH 0
#define WOFF_WIH 49152
#define WOFF_WG 98304
#define WOFF_HEADS 294912
#define WTOT 327680

__global__ __launch_bounds__(256) void convert_weights(
    const float* __restrict__ w_hh, const float* __restrict__ w_ih,
    const float* __restrict__ gnn_w, const float* __restrict__ mu_w,
    const float* __restrict__ lv_w, ushort* __restrict__ wsb)
{
  int i = blockIdx.x * 256 + threadIdx.x;
  if (i >= WTOT) return;
  float v;
  if (i < WOFF_WIH) v = w_hh[i - WOFF_WHH];
  else if (i < WOFF_WG) v = w_ih[i - WOFF_WIH];
  else if (i < WOFF_HEADS) {
    int k = i - WOFF_WG;
    int s = k >> 16;           // /65536
    int r = k & 65535;
    int c = r >> 9;            // /512
    int col = r & 511;
    int t = col >> 7;
    int j = col & 127;
    v = 2.f * gnn_w[(((size_t)s * 4 + t) * 128 + c) * 128 + j];
  } else {
    int k = i - WOFF_HEADS;
    v = (k < 16384) ? mu_w[k] : lv_w[k - 16384];
  }
  wsb[i] = f2bf(v);
}

// ---------------- CSR build ----------------
__global__ __launch_bounds__(256) void hist_dst(
    const int* __restrict__ ei, int* __restrict__ counts)
{
  int e = blockIdx.x * 256 + threadIdx.x;
  if (e >= E_EDGES) return;
  atomicAdd(&counts[ei[E_EDGES + e]], 1);
}

// hierarchical scan: per-block local exclusive scan + block totals
__global__ __launch_bounds__(1024) void scan_block(
    const int* __restrict__ counts, int* __restrict__ excl,
    int* __restrict__ bsum, int n)
{
  __shared__ int ls[1024];
  const int tid = threadIdx.x;
  const int i = blockIdx.x * 1024 + tid;
  int v = (i < n) ? counts[i] : 0;
  ls[tid] = v;
  __syncthreads();
  for (int off = 1; off < 1024; off <<= 1) {
    int t = (tid >= off) ? ls[tid - off] : 0;
    __syncthreads();
    ls[tid] += t;
    __syncthreads();
  }
  if (i < n) excl[i] = ls[tid] - v;
  if (tid == 1023) bsum[blockIdx.x] = ls[1023];
}

__global__ __launch_bounds__(64) void scan_bsums(
    const int* __restrict__ bsum, int* __restrict__ boff, int nb)
{
  __shared__ int ls[64];
  const int tid = threadIdx.x;
  int v = (tid < nb) ? bsum[tid] : 0;
  ls[tid] = v;
  __syncthreads();
  for (int off = 1; off < 64; off <<= 1) {
    int t = (tid >= off) ? ls[tid - off] : 0;
    __syncthreads();
    ls[tid] += t;
    __syncthreads();
  }
  if (tid < nb) boff[tid] = ls[tid] - v;
}

__global__ __launch_bounds__(1024) void scan_final(
    const int* __restrict__ excl, const int* __restrict__ boff,
    int* __restrict__ offsets, int* __restrict__ cursor, int n)
{
  int i = blockIdx.x * 1024 + threadIdx.x;
  if (i >= n) return;
  int o = excl[i] + boff[blockIdx.x];
  offsets[i] = o;
  cursor[i] = o;
}

__global__ __launch_bounds__(256) void fill_csr(
    const int* __restrict__ ei, const float* __restrict__ ea,
    int* __restrict__ cursor, int* __restrict__ epacked)
{
  int e = blockIdx.x * 256 + threadIdx.x;
  if (e >= E_EDGES) return;
  const float* a = ea + (size_t)e * T_TYPES;
  float bv = a[0]; int bi = 0;
#pragma unroll
  for (int t = 1; t < T_TYPES; ++t) {
    float v = a[t];
    if (v > bv) { bv = v; bi = t; }
  }
  int d = ei[E_EDGES + e];
  int pos = atomicAdd(&cursor[d], 1);
  epacked[pos] = (bi << 20) | ei[e];
}

// ---------------- gather S: S[d][t] = sum_{e in (d,t)} m[src_e]  (bf16) ----------------
// one wave per node; lane owns 2 channels; t is wave-uniform per edge.
__global__ __launch_bounds__(256) void gather_S(
    const ushort* __restrict__ m, const int* __restrict__ offsets,
    const int* __restrict__ epacked, ushort* __restrict__ S, int nNodes)
{
  const int wave = threadIdx.x >> 6, lane = threadIdx.x & 63;
  const int node = blockIdx.x * 4 + wave;
  if (node >= nNodes) return;
  const int beg = offsets[node];
  const int end = (node + 1 < nNodes) ? offsets[node + 1] : E_EDGES;
  float a0x = 0.f, a0y = 0.f, a1x = 0.f, a1y = 0.f;
  float a2x = 0.f, a2y = 0.f, a3x = 0.f, a3y = 0.f;
  for (int j = beg; j < end; ++j) {
    int p = epacked[j];
    int src = p & 0xFFFFF;
    int t = __builtin_amdgcn_readfirstlane((int)((uint)p >> 20));
    uint h = *(const uint*)(m + (size_t)src * 128 + lane * 2);
    float lo = bf2f((ushort)(h & 0xffff));
    float hi = bf2f((ushort)(h >> 16));
    if (t == 0)      { a0x += lo; a0y += hi; }
    else if (t == 1) { a1x += lo; a1y += hi; }
    else if (t == 2) { a2x += lo; a2y += hi; }
    else             { a3x += lo; a3y += hi; }
  }
  uint* sp = (uint*)(S + (size_t)node * 512 + lane * 2);
  sp[0]   = (uint)f2bf(a0x) | ((uint)f2bf(a0y) << 16);
  sp[64]  = (uint)f2bf(a1x) | ((uint)f2bf(a1y) << 16);
  sp[128] = (uint)f2bf(a2x) | ((uint)f2bf(a2y) << 16);
  sp[192] = (uint)f2bf(a3x) | ((uint)f2bf(a3y) << 16);
}

extern "C" void kernel_launch(void* const* d_in, const int* in_sizes, int n_in,
                              void* d_out, int out_size, void* d_ws, size_t ws_size,
                              hipStream_t stream) {
  const float* x     = (const float*)d_in[0];
  const int*   ei    = (const int*)d_in[1];
  const float* eattr = (const float*)d_in[2];
  const float* lin_w = (const float*)d_in[3];
  const float* lin_b = (const float*)d_in[4];
  const float* gnn_w = (const float*)d_in[5];
  const float* w_ih  = (const float*)d_in[6];
  const float* w_hh  = (const float*)d_in[7];
  const float* b_ih  = (const float*)d_in[8];
  const float* b_hh  = (const float*)d_in[9];
  const float* mu_w  = (const float*)d_in[10];
  const float* mu_b  = (const float*)d_in[11];
  const float* lv_w  = (const float*)d_in[12];
  const float* lv_b  = (const float*)d_in[13];

  char* ws = (char*)d_ws;
  size_t off = 0;
  ushort* x0b = (ushort*)(ws + off); off += (size_t)N_NODES * L * 2;        // 12.8MB
  ushort* ghb = (ushort*)(ws + off); off += (size_t)N_NODES * 3 * L * 2;    // 38.4MB
  ushort* m_b = (ushort*)(ws + off); off += (size_t)N_NODES * L * 2;        // 12.8MB
  ushort* aggb= (ushort*)(ws + off); off += (size_t)N_NODES * L * 2;        // 12.8MB
  ushort* S   = (ushort*)(ws + off); off += (size_t)N_NODES * 4 * L * 2;    // 51.2MB
  ushort* wsb = (ushort*)(ws + off); off += (size_t)WTOT * 2;               // 0.66MB
  int* counts  = (int*)(ws + off); off += 50176 * 4;
  int* excl    = (int*)(ws + off); off += 50176 * 4;
  int* offsets = (int*)(ws + off); off += 50176 * 4;
  int* cursor  = (int*)(ws + off); off += 50176 * 4;
  int* bsum    = (int*)(ws + off); off += 64 * 4;
  int* boff    = (int*)(ws + off); off += 64 * 4;
  int* epacked = (int*)(ws + off); off += (size_t)E_EDGES * 4;

  dim3 blk(256);
  const int GEMM_GRID = (N_NODES + 127) / 128;  // 391
  const int NSB = (N_NODES + 1023) / 1024;      // 49

  convert_weights<<<(WTOT + 255) / 256, blk, 0, stream>>>(
      w_hh, w_ih, gnn_w, mu_w, lv_w, wsb);

  // CSR (constant across steps)
  hipMemsetAsync(counts, 0, N_NODES * sizeof(int), stream);
  hist_dst<<<(E_EDGES + 255) / 256, blk, 0, stream>>>(ei, counts);
  scan_block<<<NSB, 1024, 0, stream>>>(counts, excl, bsum, N_NODES);
  scan_bsums<<<1, 64, 0, stream>>>(bsum, boff, NSB);
  scan_final<<<NSB, 1024, 0, stream>>>(excl, boff, offsets, cursor, N_NODES);
  fill_csr<<<(E_EDGES + 255) / 256, blk, 0, stream>>>(ei, eattr, cursor, epacked);

  // x0 = relu(x @ lin_w^T + lin_b) -> bf16
  dim3 g_x0((N_NODES + BN - 1) / BN, L / BO);
  matmul_x0<<<g_x0, blk, 0, stream>>>(x, lin_w, lin_b, x0b, N_NODES, IN_F, L);

  // gh = x0 @ w_hh^T + b_hh -> bf16
  gemm_mfma<384, 128, 0><<<GEMM_GRID, blk, 0, stream>>>(
      x0b, wsb + WOFF_WHH, b_hh, nullptr, ghb, nullptr, nullptr, nullptr, nullptr, N_NODES);

  const ushort* mcur = x0b;
  for (int s = 0; s < STEPS; ++s) {
    gather_S<<<(N_NODES + 3) / 4, blk, 0, stream>>>(mcur, offsets, epacked, S, N_NODES);
    // agg = S @ Wg[s]^T  (K=512, x2 folded into Wg)
    gemm_mfma<128, 512, 2><<<GEMM_GRID, blk, 0, stream>>>(
        S, wsb + WOFF_WG + (size_t)s * 65536, nullptr, nullptr, aggb,
        nullptr, nullptr, nullptr, nullptr, N_NODES);
    // m = relu(GRU(agg, x0))
    gemm_mfma<384, 128, 3><<<GEMM_GRID, blk, 0, stream>>>(
        aggb, wsb + WOFF_WIH, b_ih, nullptr, m_b, ghb, x0b, nullptr, nullptr, N_NODES);
    mcur = m_b;
  }

  float* mu = (float*)d_out;
  float* lv = (float*)d_out + (size_t)N_NODES * L;
  gemm_mfma<256, 128, 4><<<GEMM_GRID, blk, 0, stream>>>(
      m_b, wsb + WOFF_HEADS, mu_b, mu, nullptr, nullptr, nullptr, lv_b, lv, N_NODES);
}